// Round 1
// baseline (307.880 us; speedup 1.0000x reference)
//
#include <hip/hip_runtime.h>
#include <math.h>

// HOG (skimage-faithful): orientations=8, cell=16x16, 1x1 blocks, L2-Hys.
// Input: fake [B,3,512,512] f32 (NCHW). Output: [B, 32*32*8] f32.
//
// Block = 256 threads = 16 rows x 64 cols = 4 horizontally adjacent cells.
// Wave (64 lanes) = one row segment of 64 contiguous w -> coalesced 256B loads.
// Grid = B * 32 cellrows * 8 cellgroups.

namespace {

constexpr int Hh = 512;
constexpr int Ww = 512;
constexpr int CH = 3;

__global__ __launch_bounds__(256) void hog_kernel(const float* __restrict__ x,
                                                  float* __restrict__ out) {
    const int bx = blockIdx.x;
    const int cg = bx & 7;           // cell group: 4 cells = 64 px wide
    const int cr = (bx >> 3) & 31;   // cell row
    const int b  = bx >> 8;          // batch index
    const int tx = threadIdx.x;
    const int wl = tx & 63;          // lane within wave = w offset in strip
    const int rg = tx >> 6;          // wave id = row group (0..3)
    const int w  = cg * 64 + wl;
    const int cell = wl >> 4;        // which of the 4 cells this lane feeds

    float hist[8];
#pragma unroll
    for (int o = 0; o < 8; ++o) hist[o] = 0.f;

    const float* xb = x + (size_t)b * (CH * Hh * Ww);

    // each wave covers rows {rg, rg+4, rg+8, rg+12} of the 16-row cell band
#pragma unroll
    for (int it = 0; it < 4; ++it) {
        const int h = cr * 16 + rg + it * 4;   // wave-uniform

        float best_m = -1.f, best_gr = 0.f, best_gc = 0.f;
#pragma unroll
        for (int c = 0; c < CH; ++c) {
            const float* p = xb + (c * Hh + h) * Ww + w;
            float xu = 0.f, xd = 0.f;
            if (h > 0 && h < Hh - 1) { xu = p[-Ww]; xd = p[Ww]; }  // wave-uniform branch
            float xl = 0.f, xr = 0.f;
            if (w > 0 && w < Ww - 1) { xl = p[-1]; xr = p[1]; }
            const float grow = xd - xu;   // x[h+1]-x[h-1], 0 at border rows
            const float gcol = xr - xl;   // x[w+1]-x[w-1], 0 at border cols
            const float m = sqrtf(grow * grow + gcol * gcol);
            // strict > keeps first index on ties == np.argmax
            if (m > best_m) { best_m = m; best_gr = grow; best_gc = gcol; }
        }

        // orientation in degrees, Python-style mod 180 (matches np.mod incl.
        // the "rounds to exactly 180.0" case, which the clamp folds to bin 7)
        float ang = atan2f(best_gr, best_gc) * 57.29577951308232f;
        float ori = fmodf(ang, 180.0f);
        if (ori < 0.f) ori += 180.0f;
        int bin = (int)floorf(ori / 22.5f);
        bin = bin < 0 ? 0 : (bin > 7 ? 7 : bin);

        // branchless scatter into register histogram (no dynamic reg indexing)
#pragma unroll
        for (int o = 0; o < 8; ++o) hist[o] += (bin == o) ? best_m : 0.f;
    }

    // reduce across the 16 lanes of each cell (within this wave's 4 rows)
#pragma unroll
    for (int mask = 1; mask < 16; mask <<= 1) {
#pragma unroll
        for (int o = 0; o < 8; ++o) hist[o] += __shfl_xor(hist[o], mask, 64);
    }

    // combine the 4 waves via LDS (deterministic, no atomics)
    __shared__ float lhist[4][4][8];   // [wave][cell][bin]
    if ((wl & 15) == 0) {
#pragma unroll
        for (int o = 0; o < 8; ++o) lhist[rg][cell][o] = hist[o];
    }
    __syncthreads();

    // 32 threads: cell = tx>>3 (0..3), bin = tx&7 — finish hist + L2-Hys
    if (tx < 32) {
        const int c4 = tx >> 3, o = tx & 7;
        float hv = (lhist[0][c4][o] + lhist[1][c4][o] +
                    lhist[2][c4][o] + lhist[3][c4][o]) * (1.0f / 256.0f);

        float ss = hv * hv;
#pragma unroll
        for (int mask = 1; mask < 8; mask <<= 1) ss += __shfl_xor(ss, mask, 64);
        float n1 = hv / sqrtf(ss + 1e-10f);     // eps^2 = (1e-5)^2
        n1 = fminf(n1, 0.2f);
        float ss2 = n1 * n1;
#pragma unroll
        for (int mask = 1; mask < 8; mask <<= 1) ss2 += __shfl_xor(ss2, mask, 64);
        const float nv = n1 / sqrtf(ss2 + 1e-10f);

        // out[b, cr, cg*4+c4, o]
        const size_t oi = (((size_t)b * 32 + cr) * 32 + (cg * 4 + c4)) * 8 + o;
        out[oi] = nv;
    }
}

} // namespace

extern "C" void kernel_launch(void* const* d_in, const int* in_sizes, int n_in,
                              void* d_out, int out_size, void* d_ws, size_t ws_size,
                              hipStream_t stream) {
    (void)n_in; (void)out_size; (void)d_ws; (void)ws_size;
    const float* x = (const float*)d_in[0];
    float* out = (float*)d_out;
    const int B = in_sizes[0] / (CH * Hh * Ww);   // 64 for the bench shape
    const int grid = B * 32 * 8;                  // batch * cellrows * cellgroups
    hog_kernel<<<grid, 256, 0, stream>>>(x, out);
}

// Round 2
// 281.506 us; speedup vs baseline: 1.0937x; 1.0937x over previous
//
#include <hip/hip_runtime.h>
#include <math.h>

// HOG (skimage-faithful): orientations=8, cell=16x16, 1x1 blocks, L2-Hys.
// Input: fake [B,3,512,512] f32 (NCHW). Output: [B, 32*32*8] f32.
//
// Round 2: VALU-bound fix. atan2f/fmodf -> half-plane flip + tan22.5 sign
// tests (thermometer-coded cumulative histogram); rolling 3-row register
// window with float4 loads (8 px/lane, one wave spans the full 512-px row);
// single sqrt per pixel (channel argmax on m^2).
//
// Block = 256 threads = 4 waves; each wave = one 8-row x 512-col strip.
// Block covers 32 rows = 2 cell-rows. Grid = B * 16.

namespace {

constexpr int Hh = 512;
constexpr int Ww = 512;
constexpr int CHN = 3;
constexpr int HW = Hh * Ww;
constexpr float TAN22 = 0.41421356237309503f;  // tan(22.5 deg) = sqrt(2)-1

__device__ __forceinline__ void load_row(const float* __restrict__ xb,
                                         int h, int lane, float dst[CHN][8]) {
    const int hl = h < 0 ? 0 : (h > Hh - 1 ? Hh - 1 : h);  // clamped rows only
#pragma unroll                                             // feed forced-zero grow
    for (int ch = 0; ch < CHN; ++ch) {
        const float4* p =
            (const float4*)(xb + (size_t)ch * HW + (size_t)hl * Ww) + (lane << 1);
        const float4 a = p[0];
        const float4 b = p[1];
        dst[ch][0] = a.x; dst[ch][1] = a.y; dst[ch][2] = a.z; dst[ch][3] = a.w;
        dst[ch][4] = b.x; dst[ch][5] = b.y; dst[ch][6] = b.z; dst[ch][7] = b.w;
    }
}

__global__ __launch_bounds__(256) void hog_kernel(const float* __restrict__ x,
                                                  float* __restrict__ out) {
    const int b     = blockIdx.x >> 4;
    const int band2 = blockIdx.x & 15;       // 32-row super-band = 2 cell rows
    const int tx    = threadIdx.x;
    const int lane  = tx & 63;
    const int rg    = tx >> 6;               // wave id = 8-row strip within band
    const int r0    = band2 * 32 + rg * 8;   // first pixel row of this strip
    const bool isL0  = (lane == 0);
    const bool isL63 = (lane == 63);

    const float* xb = x + (size_t)b * (CHN * HW);

    float c[8];                              // cumulative thermometer histogram
#pragma unroll
    for (int o = 0; o < 8; ++o) c[o] = 0.f;

    float win[3][CHN][8];                    // rolling rows: prev/cur/next slots
    load_row(xb, r0 - 1, lane, win[0]);
    load_row(xb, r0,     lane, win[1]);
    load_row(xb, r0 + 1, lane, win[2]);

#pragma unroll
    for (int hh = 0; hh < 8; ++hh) {
        const int h = r0 + hh;
        float (*prev)[8] = win[hh % 3];
        float (*cur)[8]  = win[(hh + 1) % 3];
        float (*next)[8] = win[(hh + 2) % 3];
        const bool rowEdge = (h == 0) | (h == Hh - 1);   // wave-uniform

        // vertical gradients first (consume prev), then recycle its slot
        float grow[CHN][8];
#pragma unroll
        for (int ch = 0; ch < CHN; ++ch)
#pragma unroll
            for (int i = 0; i < 8; ++i)
                grow[ch][i] = rowEdge ? 0.f : next[ch][i] - prev[ch][i];

        if (hh < 7) load_row(xb, h + 2, lane, win[hh % 3]);  // prefetch

        // horizontal halo across lanes (wave spans the full row: no strip halo)
        float shL[CHN], shR[CHN];
#pragma unroll
        for (int ch = 0; ch < CHN; ++ch) {
            shL[ch] = __shfl_up(cur[ch][7], 1, 64);    // lane-1's w=8l-1
            shR[ch] = __shfl_down(cur[ch][0], 1, 64);  // lane+1's w=8l+8
        }

#pragma unroll
        for (int i = 0; i < 8; ++i) {
            float bm2 = -1.f, bgr = 0.f, bgc = 0.f;
#pragma unroll
            for (int ch = 0; ch < CHN; ++ch) {
                const float gl = (i == 0) ? shL[ch] : cur[ch][i - 1];
                const float gr_ = (i == 7) ? shR[ch] : cur[ch][i + 1];
                float gcol = gr_ - gl;
                if (i == 0) gcol = isL0 ? 0.f : gcol;    // w==0 border
                if (i == 7) gcol = isL63 ? 0.f : gcol;   // w==511 border
                const float gv = grow[ch][i];
                const float m2 = fmaf(gv, gv, gcol * gcol);
                if (m2 > bm2) { bm2 = m2; bgr = gv; bgc = gcol; }  // first-max
            }
            const float m = sqrtf(bm2);

            // flip into upper half-plane; (gr==0, gc<0) -> angle 180 -> bin 0
            const bool flip = (bgr < 0.f) | ((bgr == 0.f) & (bgc < 0.f));
            const float bb = flip ? -bgr : bgr;          // >= 0
            const float A  = flip ? -bgc : bgc;
            const float Aa = fabsf(A);
            const float p1 = Aa * TAN22;
            const float p2 = bb * TAN22;
            const bool q2  = (A <= 0.f);                 // ori >= 90
            const bool ge1 = (bb >= p1), ge2 = (bb >= Aa), ge3 = (p2 >= Aa);
            const bool gt1 = (bb > p1),  gt2 = (bb > Aa),  gt3 = (p2 > Aa);
            // thermometer: b_k == (ori >= 22.5k); hist recovered by differencing
            c[0] += m;
            c[1] += (q2 | ge1) ? m : 0.f;
            c[2] += (q2 | ge2) ? m : 0.f;
            c[3] += (q2 | ge3) ? m : 0.f;
            c[4] += q2 ? m : 0.f;
            c[5] += (q2 & !gt3) ? m : 0.f;
            c[6] += (q2 & !gt2) ? m : 0.f;
            c[7] += (q2 & !gt1) ? m : 0.f;
        }
    }

    // lane pair (2c,2c+1) = one 16-col cell; reduce pairs in-register
#pragma unroll
    for (int o = 0; o < 8; ++o) c[o] += __shfl_xor(c[o], 1, 64);

    __shared__ float lhist[4][32][9];        // [strip][cell][bin], col 8 = 0 pad
    if (tx < 128) lhist[tx >> 5][tx & 31][8] = 0.f;
    if ((lane & 1) == 0) {
        const int cellc = lane >> 1;
#pragma unroll
        for (int o = 0; o < 8; ++o) lhist[rg][cellc][o] = c[o];
    }
    __syncthreads();

    // 256 threads -> (cell, bin); two cell-rows (strips {0,1} and {2,3})
    const int cell = tx >> 3;
    const int o    = tx & 7;
#pragma unroll
    for (int band = 0; band < 2; ++band) {
        const float c_o  = lhist[2 * band][cell][o]     + lhist[2 * band + 1][cell][o];
        const float c_o1 = lhist[2 * band][cell][o + 1] + lhist[2 * band + 1][cell][o + 1];
        const float hv = (c_o - c_o1) * (1.0f / 256.0f);   // cell mean

        float ss = hv * hv;                   // L2-Hys over the 8-bin group
        ss += __shfl_xor(ss, 1, 64);
        ss += __shfl_xor(ss, 2, 64);
        ss += __shfl_xor(ss, 4, 64);
        float n1 = hv / sqrtf(ss + 1e-10f);   // eps^2 = (1e-5)^2
        n1 = fminf(n1, 0.2f);
        float s2 = n1 * n1;
        s2 += __shfl_xor(s2, 1, 64);
        s2 += __shfl_xor(s2, 2, 64);
        s2 += __shfl_xor(s2, 4, 64);
        const float nv = n1 / sqrtf(s2 + 1e-10f);

        const size_t oi =
            (((size_t)b * 32 + (band2 * 2 + band)) * 32 + cell) * 8 + o;
        out[oi] = nv;
    }
}

} // namespace

extern "C" void kernel_launch(void* const* d_in, const int* in_sizes, int n_in,
                              void* d_out, int out_size, void* d_ws, size_t ws_size,
                              hipStream_t stream) {
    (void)n_in; (void)out_size; (void)d_ws; (void)ws_size;
    const float* x = (const float*)d_in[0];
    float* out = (float*)d_out;
    const int B = in_sizes[0] / (CHN * HW);   // 64 for the bench shape
    const int grid = B * 16;                  // batch * 32-row super-bands
    hog_kernel<<<grid, 256, 0, stream>>>(x, out);
}